// Round 1
// baseline (72.558 us; speedup 1.0000x reference)
//
#include <hip/hip_runtime.h>

// Tree-MLP, fp32 vector baseline.
// One thread = one sample. DFS traversal of the tree keeps the live
// activation set <= ~96 floats. Weights/biases are read via wave-uniform
// addresses so the compiler emits s_load -> SGPR, and each FMA is
// v_fma_f32 vdst, sweight, vin, vdst (1 SGPR operand per VALU op: legal).

__device__ __forceinline__ float relu_(float a) { return fmaxf(a, 0.0f); }

// Linear(2 -> 16) + relu. W layout: W[c*16 + h], c in {0,1}.
__device__ __forceinline__ void node2(float x0, float x1,
                                      const float* __restrict__ W,
                                      const float* __restrict__ b,
                                      float* __restrict__ o) {
#pragma unroll
  for (int h = 0; h < 16; ++h)
    o[h] = relu_(fmaf(x0, W[h], fmaf(x1, W[16 + h], b[h])));
}

// Linear(32 -> 16) + relu. Inputs are two 16-vectors (concat). W[c*16 + h].
__device__ __forceinline__ void node32(const float* __restrict__ l,
                                       const float* __restrict__ r,
                                       const float* __restrict__ W,
                                       const float* __restrict__ b,
                                       float* __restrict__ o) {
#pragma unroll
  for (int h = 0; h < 16; ++h) {
    float a = b[h];
#pragma unroll
    for (int c = 0; c < 16; ++c) a = fmaf(l[c], W[c * 16 + h], a);
#pragma unroll
    for (int c = 0; c < 16; ++c) a = fmaf(r[c], W[(c + 16) * 16 + h], a);
    o[h] = relu_(a);
  }
}

__global__ __launch_bounds__(256) void tree_mlp_f32(
    const float* __restrict__ x,
    const float* __restrict__ W1, const float* __restrict__ b1,
    const float* __restrict__ W2, const float* __restrict__ b2,
    const float* __restrict__ W3, const float* __restrict__ b3,
    const float* __restrict__ W4, const float* __restrict__ b4,
    float* __restrict__ out, int nB) {
  int tid = blockIdx.x * blockDim.x + threadIdx.x;
  if (tid >= nB) return;

  // 4x float4 loads: each lane reads its sample's 16 contiguous floats.
  const float4* xv = reinterpret_cast<const float4*>(x) + (size_t)tid * 4;
  float4 p0 = xv[0], p1 = xv[1], p2 = xv[2], p3 = xv[3];
  float xr[16] = {p0.x, p0.y, p0.z, p0.w, p1.x, p1.y, p1.z, p1.w,
                  p2.x, p2.y, p2.z, p2.w, p3.x, p3.y, p3.z, p3.w};

  float t0[16], t1[16], u0[16], u1[16], v0[16], v1[16];

  // ---- left half of the tree ----
  node2(xr[0], xr[1], W1 + 0 * 32, b1 + 0 * 16, t0);
  node2(xr[2], xr[3], W1 + 1 * 32, b1 + 1 * 16, t1);
  node32(t0, t1, W2 + 0 * 512, b2 + 0 * 16, u0);
  node2(xr[4], xr[5], W1 + 2 * 32, b1 + 2 * 16, t0);
  node2(xr[6], xr[7], W1 + 3 * 32, b1 + 3 * 16, t1);
  node32(t0, t1, W2 + 1 * 512, b2 + 1 * 16, u1);
  node32(u0, u1, W3 + 0 * 512, b3 + 0 * 16, v0);

  // ---- right half ----
  node2(xr[8], xr[9], W1 + 4 * 32, b1 + 4 * 16, t0);
  node2(xr[10], xr[11], W1 + 5 * 32, b1 + 5 * 16, t1);
  node32(t0, t1, W2 + 2 * 512, b2 + 2 * 16, u0);
  node2(xr[12], xr[13], W1 + 6 * 32, b1 + 6 * 16, t0);
  node2(xr[14], xr[15], W1 + 7 * 32, b1 + 7 * 16, t1);
  node32(t0, t1, W2 + 3 * 512, b2 + 3 * 16, u1);
  node32(u0, u1, W3 + 1 * 512, b3 + 1 * 16, v1);

  // ---- root ----
  float o[16];
  node32(v0, v1, W4, b4, o);

  float4* ov = reinterpret_cast<float4*>(out) + (size_t)tid * 4;
  ov[0] = make_float4(o[0], o[1], o[2], o[3]);
  ov[1] = make_float4(o[4], o[5], o[6], o[7]);
  ov[2] = make_float4(o[8], o[9], o[10], o[11]);
  ov[3] = make_float4(o[12], o[13], o[14], o[15]);
}

extern "C" void kernel_launch(void* const* d_in, const int* in_sizes, int n_in,
                              void* d_out, int out_size, void* d_ws, size_t ws_size,
                              hipStream_t stream) {
  const float* x  = (const float*)d_in[0];
  const float* W1 = (const float*)d_in[1];
  const float* b1 = (const float*)d_in[2];
  const float* W2 = (const float*)d_in[3];
  const float* b2 = (const float*)d_in[4];
  const float* W3 = (const float*)d_in[5];
  const float* b3 = (const float*)d_in[6];
  const float* W4 = (const float*)d_in[7];
  const float* b4 = (const float*)d_in[8];
  float* out = (float*)d_out;

  int nB = in_sizes[0] / 16;  // 524288
  const int block = 256;
  int grid = (nB + block - 1) / block;
  tree_mlp_f32<<<grid, block, 0, stream>>>(x, W1, b1, W2, b2, W3, b3, W4, b4,
                                           out, nB);
}

// Round 2
// 29.895 us; speedup vs baseline: 2.4271x; 2.4271x over previous
//
#include <hip/hip_runtime.h>
#include <hip/hip_bf16.h>

// Tree-MLP via bf16 MFMA (16x16x32), fp32 accumulate.
// One wave processes 16-sample tiles. Swapped product per node:
//   D[n][m] = sum_k Wt[n][k] * X[m][k]   (A = W^T fragment, B = X^T fragment)
// so D layout (col=sample=lane&15, row=4g+reg) IS the next layer's B fragment
// under the k-slot map k(g,j) = 4g+j (j<4) | 16+4g+(j-4) (j>=4) — no shuffles.
// The same k-map is applied to the A-side (weights) at hoist time, which is
// all MFMA requires (contraction is invariant to a consistent k permutation).

typedef __attribute__((ext_vector_type(8))) short bf16x8;   // 8 bf16 = 4 VGPRs
typedef __attribute__((ext_vector_type(4))) float f32x4;    // 4 fp32

__device__ __forceinline__ short bfr(float f) {
  return (short)__builtin_bit_cast(unsigned short, __float2bfloat16(f));
}
__device__ __forceinline__ float relu_(float a) { return fmaxf(a, 0.0f); }

__global__ __launch_bounds__(256) void tree_mlp_mfma(
    const float* __restrict__ x,
    const float* __restrict__ W1, const float* __restrict__ b1,
    const float* __restrict__ W2, const float* __restrict__ b2,
    const float* __restrict__ W3, const float* __restrict__ b3,
    const float* __restrict__ W4, const float* __restrict__ b4,
    float* __restrict__ out, int ntiles) {
  const int lane = threadIdx.x & 63;
  const int n = lane & 15;   // A-side row (output feature) / B-side col (sample)
  const int g = lane >> 4;   // lane group 0..3

  const int wpb = blockDim.x >> 6;
  const int gw = blockIdx.x * wpb + (threadIdx.x >> 6);
  const int nw = gridDim.x * wpb;

  // ---------------- hoist weight fragments into VGPRs ----------------
  // Level 1: Linear(2->16) per node i; nonzero A only at k=2i,2i+1.
  // Bias folded into k=16 (B-side provides a constant 1.0 there).
  bf16x8 w1f[8];
#pragma unroll
  for (int i = 0; i < 8; ++i) {
    bf16x8 f;
#pragma unroll
    for (int j = 0; j < 8; ++j) f[j] = (short)0;
#pragma unroll
    for (int j = 0; j < 4; ++j) {
      int k = 4 * g + j;
      float v = 0.0f;
      if (k == 2 * i)     v = W1[i * 32 + n];        // W1[i][0][n]
      if (k == 2 * i + 1) v = W1[i * 32 + 16 + n];   // W1[i][1][n]
      f[j] = bfr(v);
    }
    if (g == 0) f[4] = bfr(b1[i * 16 + n]);          // k==16 bias slot
    w1f[i] = f;
  }

  // Levels 2/3/root: Linear(32->16); A[n][k] = W[k][n] under the k-map.
  bf16x8 w2f[4]; f32x4 c2[4];
#pragma unroll
  for (int i = 0; i < 4; ++i) {
    bf16x8 f;
#pragma unroll
    for (int j = 0; j < 4; ++j) f[j]     = bfr(W2[i * 512 + (4 * g + j) * 16 + n]);
#pragma unroll
    for (int j = 0; j < 4; ++j) f[4 + j] = bfr(W2[i * 512 + (16 + 4 * g + j) * 16 + n]);
    w2f[i] = f;
#pragma unroll
    for (int r = 0; r < 4; ++r) c2[i][r] = b2[i * 16 + 4 * g + r];
  }
  bf16x8 w3f[2]; f32x4 c3[2];
#pragma unroll
  for (int i = 0; i < 2; ++i) {
    bf16x8 f;
#pragma unroll
    for (int j = 0; j < 4; ++j) f[j]     = bfr(W3[i * 512 + (4 * g + j) * 16 + n]);
#pragma unroll
    for (int j = 0; j < 4; ++j) f[4 + j] = bfr(W3[i * 512 + (16 + 4 * g + j) * 16 + n]);
    w3f[i] = f;
#pragma unroll
    for (int r = 0; r < 4; ++r) c3[i][r] = b3[i * 16 + 4 * g + r];
  }
  bf16x8 w4f; f32x4 c4;
  {
    bf16x8 f;
#pragma unroll
    for (int j = 0; j < 4; ++j) f[j]     = bfr(W4[(4 * g + j) * 16 + n]);
#pragma unroll
    for (int j = 0; j < 4; ++j) f[4 + j] = bfr(W4[(16 + 4 * g + j) * 16 + n]);
    w4f = f;
#pragma unroll
    for (int r = 0; r < 4; ++r) c4[r] = b4[4 * g + r];
  }

  const short one_bf = bfr(1.0f);
  const f32x4* __restrict__ xf = reinterpret_cast<const f32x4*>(x);
  f32x4* __restrict__ of = reinterpret_cast<f32x4*>(out);

  int t = gw;
  if (t >= ntiles) return;
  // lane reads sample row (16t + n), features [4g, 4g+3] -> one 16B load
  f32x4 xv = xf[(size_t)(t * 16 + n) * 4 + g];

  while (t < ntiles) {
    const int tn = t + nw;
    f32x4 xnext = xv;
    if (tn < ntiles) xnext = xf[(size_t)(tn * 16 + n) * 4 + g];  // prefetch

    // B fragment for level 1 (X^T), K=16 padded; k=16 slot carries 1.0
    bf16x8 xb;
    xb[0] = bfr(xv[0]); xb[1] = bfr(xv[1]); xb[2] = bfr(xv[2]); xb[3] = bfr(xv[3]);
    xb[4] = (g == 0) ? one_bf : (short)0;
    xb[5] = 0; xb[6] = 0; xb[7] = 0;

    const f32x4 zero = {0.f, 0.f, 0.f, 0.f};
    f32x4 a1[8];
#pragma unroll
    for (int i = 0; i < 8; ++i)
      a1[i] = __builtin_amdgcn_mfma_f32_16x16x32_bf16(w1f[i], xb, zero, 0, 0, 0);

    f32x4 a2[4];
#pragma unroll
    for (int i = 0; i < 4; ++i) {
      bf16x8 hb;
#pragma unroll
      for (int r = 0; r < 4; ++r) {
        hb[r]     = bfr(relu_(a1[2 * i][r]));
        hb[4 + r] = bfr(relu_(a1[2 * i + 1][r]));
      }
      a2[i] = __builtin_amdgcn_mfma_f32_16x16x32_bf16(w2f[i], hb, c2[i], 0, 0, 0);
    }

    f32x4 a3[2];
#pragma unroll
    for (int i = 0; i < 2; ++i) {
      bf16x8 hb;
#pragma unroll
      for (int r = 0; r < 4; ++r) {
        hb[r]     = bfr(relu_(a2[2 * i][r]));
        hb[4 + r] = bfr(relu_(a2[2 * i + 1][r]));
      }
      a3[i] = __builtin_amdgcn_mfma_f32_16x16x32_bf16(w3f[i], hb, c3[i], 0, 0, 0);
    }

    bf16x8 hb4;
#pragma unroll
    for (int r = 0; r < 4; ++r) {
      hb4[r]     = bfr(relu_(a3[0][r]));
      hb4[4 + r] = bfr(relu_(a3[1][r]));
    }
    f32x4 a4 = __builtin_amdgcn_mfma_f32_16x16x32_bf16(w4f, hb4, c4, 0, 0, 0);

    f32x4 o;
#pragma unroll
    for (int r = 0; r < 4; ++r) o[r] = relu_(a4[r]);
    __builtin_nontemporal_store(o, &of[(size_t)(t * 16 + n) * 4 + g]);

    t = tn;
    xv = xnext;
  }
}

extern "C" void kernel_launch(void* const* d_in, const int* in_sizes, int n_in,
                              void* d_out, int out_size, void* d_ws, size_t ws_size,
                              hipStream_t stream) {
  const float* x  = (const float*)d_in[0];
  const float* W1 = (const float*)d_in[1];
  const float* b1 = (const float*)d_in[2];
  const float* W2 = (const float*)d_in[3];
  const float* b2 = (const float*)d_in[4];
  const float* W3 = (const float*)d_in[5];
  const float* b3 = (const float*)d_in[6];
  const float* W4 = (const float*)d_in[7];
  const float* b4 = (const float*)d_in[8];
  float* out = (float*)d_out;

  const int ntiles = in_sizes[0] / 256;   // 16 samples x 16 features per tile
  const int block = 256;                  // 4 waves/block
  const int grid = 1024;                  // 4096 waves -> 8 tiles/wave
  tree_mlp_mfma<<<grid, block, 0, stream>>>(x, W1, b1, W2, b2, W3, b3, W4, b4,
                                            out, ntiles);
}

// Round 3
// 24.345 us; speedup vs baseline: 2.9804x; 1.2280x over previous
//
#include <hip/hip_runtime.h>
#include <hip/hip_bf16.h>

// Tree-MLP via bf16 MFMA (16x16x32), fp32 accumulate. v3: latency-focused.
//  - swapped product D[n][m] = W^T X^T per node; D layout (col=sample, row=4g+r)
//    feeds the next layer's B fragment under k-map k(g,j)=4g+j | 16+4g+(j-4).
//  - 2-deep x prefetch (load t+2*nw while computing t): load sits ~2 full
//    iterations ahead of use >> 900cy HBM latency.
//  - reg diet: biases packed bf16 (14 regs vs 28), L1 pair -> L2 interleave
//    caps live a1 at 8 regs, __launch_bounds__(256,3) guarantees 3 waves/SIMD.

typedef __attribute__((ext_vector_type(8))) short bf16x8;   // 8 bf16 = 4 VGPRs
typedef __attribute__((ext_vector_type(4))) short bf16x4;   // 4 bf16 = 2 VGPRs
typedef __attribute__((ext_vector_type(4))) float f32x4;    // 4 fp32

__device__ __forceinline__ short bfr(float f) {
  return (short)__builtin_bit_cast(unsigned short, __float2bfloat16(f));
}
__device__ __forceinline__ float bf2f(short s) {
  unsigned u = ((unsigned)(unsigned short)s) << 16;
  return __builtin_bit_cast(float, u);
}
__device__ __forceinline__ float relu_(float a) { return fmaxf(a, 0.0f); }
__device__ __forceinline__ f32x4 unpk(bf16x4 p) {
  f32x4 c;
#pragma unroll
  for (int r = 0; r < 4; ++r) c[r] = bf2f(p[r]);
  return c;
}

__global__ __launch_bounds__(256, 3) void tree_mlp_mfma3(
    const float* __restrict__ x,
    const float* __restrict__ W1, const float* __restrict__ b1,
    const float* __restrict__ W2, const float* __restrict__ b2,
    const float* __restrict__ W3, const float* __restrict__ b3,
    const float* __restrict__ W4, const float* __restrict__ b4,
    float* __restrict__ out, int ntiles) {
  const int lane = threadIdx.x & 63;
  const int n = lane & 15;   // output feature row / sample col
  const int g = lane >> 4;   // lane group 0..3

  const int wpb = blockDim.x >> 6;
  const int gw = blockIdx.x * wpb + (threadIdx.x >> 6);
  const int nw = gridDim.x * wpb;

  // ---------------- weight fragments (loop-invariant) ----------------
  bf16x8 w1f[8];
#pragma unroll
  for (int i = 0; i < 8; ++i) {
    bf16x8 f;
#pragma unroll
    for (int j = 0; j < 8; ++j) f[j] = (short)0;
#pragma unroll
    for (int j = 0; j < 4; ++j) {
      int k = 4 * g + j;
      float v = 0.0f;
      if (k == 2 * i)     v = W1[i * 32 + n];
      if (k == 2 * i + 1) v = W1[i * 32 + 16 + n];
      f[j] = bfr(v);
    }
    if (g == 0) f[4] = bfr(b1[i * 16 + n]);   // bias in k==16 slot
    w1f[i] = f;
  }
  bf16x8 w2f[4]; bf16x4 c2p[4];
#pragma unroll
  for (int i = 0; i < 4; ++i) {
    bf16x8 f;
#pragma unroll
    for (int j = 0; j < 4; ++j) f[j]     = bfr(W2[i * 512 + (4 * g + j) * 16 + n]);
#pragma unroll
    for (int j = 0; j < 4; ++j) f[4 + j] = bfr(W2[i * 512 + (16 + 4 * g + j) * 16 + n]);
    w2f[i] = f;
#pragma unroll
    for (int r = 0; r < 4; ++r) c2p[i][r] = bfr(b2[i * 16 + 4 * g + r]);
  }
  bf16x8 w3f[2]; bf16x4 c3p[2];
#pragma unroll
  for (int i = 0; i < 2; ++i) {
    bf16x8 f;
#pragma unroll
    for (int j = 0; j < 4; ++j) f[j]     = bfr(W3[i * 512 + (4 * g + j) * 16 + n]);
#pragma unroll
    for (int j = 0; j < 4; ++j) f[4 + j] = bfr(W3[i * 512 + (16 + 4 * g + j) * 16 + n]);
    w3f[i] = f;
#pragma unroll
    for (int r = 0; r < 4; ++r) c3p[i][r] = bfr(b3[i * 16 + 4 * g + r]);
  }
  bf16x8 w4f; bf16x4 c4p;
  {
    bf16x8 f;
#pragma unroll
    for (int j = 0; j < 4; ++j) f[j]     = bfr(W4[(4 * g + j) * 16 + n]);
#pragma unroll
    for (int j = 0; j < 4; ++j) f[4 + j] = bfr(W4[(16 + 4 * g + j) * 16 + n]);
    w4f = f;
#pragma unroll
    for (int r = 0; r < 4; ++r) c4p[r] = bfr(b4[4 * g + r]);
  }

  const short bias_slot = (g == 0) ? bfr(1.0f) : (short)0;
  const f32x4* __restrict__ xf = reinterpret_cast<const f32x4*>(x);
  f32x4* __restrict__ of = reinterpret_cast<f32x4*>(out);

  int t = gw;
  if (t >= ntiles) return;

  // lane (n,g) owns sample row 16t+n, features [4g,4g+3] -> one 16B load
  f32x4 xa = __builtin_nontemporal_load(&xf[(size_t)(t * 16 + n) * 4 + g]);
  f32x4 xb1 = xa;
  if (t + nw < ntiles)
    xb1 = __builtin_nontemporal_load(&xf[(size_t)((t + nw) * 16 + n) * 4 + g]);

  for (; t < ntiles; t += nw) {
    f32x4 xc = xb1;
    if (t + 2 * nw < ntiles)
      xc = __builtin_nontemporal_load(&xf[(size_t)((t + 2 * nw) * 16 + n) * 4 + g]);

    // level-1 B fragment: x^T with constant-1 bias feature at k==16
    bf16x8 xbf;
    xbf[0] = bfr(xa[0]); xbf[1] = bfr(xa[1]);
    xbf[2] = bfr(xa[2]); xbf[3] = bfr(xa[3]);
    xbf[4] = bias_slot; xbf[5] = 0; xbf[6] = 0; xbf[7] = 0;

    const f32x4 zero = {0.f, 0.f, 0.f, 0.f};

    // L1 pair -> L2 interleave keeps only one a1-pair live at a time
    f32x4 a2[4];
#pragma unroll
    for (int i = 0; i < 4; ++i) {
      f32x4 aL = __builtin_amdgcn_mfma_f32_16x16x32_bf16(w1f[2 * i],     xbf, zero, 0, 0, 0);
      f32x4 aR = __builtin_amdgcn_mfma_f32_16x16x32_bf16(w1f[2 * i + 1], xbf, zero, 0, 0, 0);
      bf16x8 hb;
#pragma unroll
      for (int r = 0; r < 4; ++r) {
        hb[r]     = bfr(relu_(aL[r]));
        hb[4 + r] = bfr(relu_(aR[r]));
      }
      a2[i] = __builtin_amdgcn_mfma_f32_16x16x32_bf16(w2f[i], hb, unpk(c2p[i]), 0, 0, 0);
    }

    f32x4 a3[2];
#pragma unroll
    for (int i = 0; i < 2; ++i) {
      bf16x8 hb;
#pragma unroll
      for (int r = 0; r < 4; ++r) {
        hb[r]     = bfr(relu_(a2[2 * i][r]));
        hb[4 + r] = bfr(relu_(a2[2 * i + 1][r]));
      }
      a3[i] = __builtin_amdgcn_mfma_f32_16x16x32_bf16(w3f[i], hb, unpk(c3p[i]), 0, 0, 0);
    }

    bf16x8 hb4;
#pragma unroll
    for (int r = 0; r < 4; ++r) {
      hb4[r]     = bfr(relu_(a3[0][r]));
      hb4[4 + r] = bfr(relu_(a3[1][r]));
    }
    f32x4 a4 = __builtin_amdgcn_mfma_f32_16x16x32_bf16(w4f, hb4, unpk(c4p), 0, 0, 0);

    f32x4 o;
#pragma unroll
    for (int r = 0; r < 4; ++r) o[r] = relu_(a4[r]);
    __builtin_nontemporal_store(o, &of[(size_t)(t * 16 + n) * 4 + g]);

    xa = xb1;
    xb1 = xc;
  }
}

extern "C" void kernel_launch(void* const* d_in, const int* in_sizes, int n_in,
                              void* d_out, int out_size, void* d_ws, size_t ws_size,
                              hipStream_t stream) {
  const float* x  = (const float*)d_in[0];
  const float* W1 = (const float*)d_in[1];
  const float* b1 = (const float*)d_in[2];
  const float* W2 = (const float*)d_in[3];
  const float* b2 = (const float*)d_in[4];
  const float* W3 = (const float*)d_in[5];
  const float* b3 = (const float*)d_in[6];
  const float* W4 = (const float*)d_in[7];
  const float* b4 = (const float*)d_in[8];
  float* out = (float*)d_out;

  const int ntiles = in_sizes[0] / 256;   // 16 samples x 16 features per tile
  const int block = 256;                  // 4 waves/block
  const int grid = 768;                   // 3 blocks/CU resident (256,3 bound)
  tree_mlp_mfma3<<<grid, block, 0, stream>>>(x, W1, b1, W2, b2, W3, b3, W4, b4,
                                             out, ntiles);
}